// Round 1
// baseline (153.040 us; speedup 1.0000x reference)
//
#include <hip/hip_runtime.h>

// DynamicMaskHead: fused CondInst mask-head MLP + aligned_bilinear x2 upsample.
// Grid: 512 blocks = 256 instances x 2 halves. Block: 512 threads.
// LDS: 65 logit rows (halo of 1) x 192 cols = 49,920 B -> 2 blocks/CU.

#define HI 128
#define WI 192
#define HW_ (HI * WI)        // 24576
#define NP 169
#define NOUT_W 384
#define NOUT_H 256

__global__ __launch_bounds__(512, 4) void dynmask_kernel(
    const float* __restrict__ feats,    // [2,8,128,192]
    const float* __restrict__ params,   // [256,169]
    const float* __restrict__ locs,     // [256,2]
    const float* __restrict__ soi,      // [5]
    const int*   __restrict__ im_inds,  // [256]
    const int*   __restrict__ lvls,     // [256]
    float*       __restrict__ out)      // [256,1,256,384]
{
    __shared__ __align__(16) float L[65 * WI];   // logit rows R0..R0+64

    const int b  = blockIdx.x;
    const int n  = b >> 1;       // instance
    const int hh = b & 1;        // half (0: out rows 0..127, 1: 128..255)
    const int t  = threadIdx.x;
    const int R0 = hh ? 63 : 0;  // first logit row held in LDS

    const int   im    = im_inds[n];
    const float s     = soi[lvls[n]];
    const float inv_s = 1.0f / s;
    const float ixv   = locs[2 * n + 0];
    const float iyv   = locs[2 * n + 1];
    const float* __restrict__ P = params + n * NP;   // uniform -> s_loads
    const float* __restrict__ F = feats + im * (8 * HW_);

    // rel_x(px) = (ixv - (px*8+4))/s = ax - px*step ; rel_y analogous
    const float step = 8.0f * inv_s;
    const float ax   = (ixv - 4.0f) * inv_s;
    const float ay   = (iyv - 4.0f) * inv_s;

    // ---------------- Phase 1: MLP -> logits in LDS ----------------
    // 65 rows * 192 cols = 12480 px = 3120 chunks of 4 px (contiguous).
    for (int idx = t; idx < 3120; idx += 512) {
        const int p   = R0 * WI + (idx << 2);    // global pixel (contiguous)
        const int py  = p / WI;
        const int px0 = p - py * WI;
        const float ry  = ay - (float)py * step;
        const float rx0 = ax - (float)px0 * step;
        const float rx[4] = {rx0, rx0 - step, rx0 - 2.0f * step, rx0 - 3.0f * step};

        float fv[8][4];
        #pragma unroll
        for (int k = 0; k < 8; ++k) {
            const float4 v = *reinterpret_cast<const float4*>(F + k * HW_ + p);
            fv[k][0] = v.x; fv[k][1] = v.y; fv[k][2] = v.z; fv[k][3] = v.w;
        }

        // layer 0: 10 -> 8, relu.  w0[o][i]=P[o*10+i], b0[o]=P[152+o]
        float h0[8][4];
        #pragma unroll
        for (int o = 0; o < 8; ++o) {
            const float base = fmaf(P[o * 10 + 1], ry, P[152 + o]);
            const float wx   = P[o * 10 + 0];
            #pragma unroll
            for (int j = 0; j < 4; ++j) h0[o][j] = fmaf(wx, rx[j], base);
            #pragma unroll
            for (int k = 0; k < 8; ++k) {
                const float w = P[o * 10 + 2 + k];
                #pragma unroll
                for (int j = 0; j < 4; ++j) h0[o][j] = fmaf(w, fv[k][j], h0[o][j]);
            }
            #pragma unroll
            for (int j = 0; j < 4; ++j) h0[o][j] = fmaxf(h0[o][j], 0.0f);
        }

        // layer 1: 8 -> 8, relu.  w1[o][i]=P[80+o*8+i], b1[o]=P[160+o]
        float h1[8][4];
        #pragma unroll
        for (int o = 0; o < 8; ++o) {
            const float bb = P[160 + o];
            #pragma unroll
            for (int j = 0; j < 4; ++j) h1[o][j] = bb;
            #pragma unroll
            for (int i = 0; i < 8; ++i) {
                const float w = P[80 + o * 8 + i];
                #pragma unroll
                for (int j = 0; j < 4; ++j) h1[o][j] = fmaf(w, h0[i][j], h1[o][j]);
            }
            #pragma unroll
            for (int j = 0; j < 4; ++j) h1[o][j] = fmaxf(h1[o][j], 0.0f);
        }

        // layer 2: 8 -> 1.  w2[i]=P[144+i], b2=P[168]
        float lg[4];
        const float b2 = P[168];
        #pragma unroll
        for (int j = 0; j < 4; ++j) lg[j] = b2;
        #pragma unroll
        for (int i = 0; i < 8; ++i) {
            const float w = P[144 + i];
            #pragma unroll
            for (int j = 0; j < 4; ++j) lg[j] = fmaf(w, h1[i][j], lg[j]);
        }

        float4 st; st.x = lg[0]; st.y = lg[1]; st.z = lg[2]; st.w = lg[3];
        *reinterpret_cast<float4*>(&L[idx << 2]) = st;
    }

    __syncthreads();

    // ---------------- Phase 2: aligned_bilinear x2 ----------------
    // out[y][x] = interp[max(y-1,0)][max(x-1,0)]
    //   rows: ry0=(iy)>>1, fy=iy&1 -> row ry0 or avg(ry0, min(ry0+1,127))
    //   cols: out[2m]=0.5*(v[m-1]+v[m]) (clamp m-1>=0), out[2m+1]=v[m]
    // Each thread: 8 output px from a float4 of v (+1 left neighbor).
    const int Y0 = hh << 7;
    float* __restrict__ O = out + n * (NOUT_H * NOUT_W) + Y0 * NOUT_W;
    for (int g = t; g < 6144; g += 512) {     // 128 rows * 48 groups
        const int yq = g / 48;
        const int c  = g - yq * 48;
        const int y  = Y0 + yq;
        const int iy2 = (y == 0) ? 0 : (y - 1);
        const int ry0 = iy2 >> 1;
        const int fy  = iy2 & 1;
        const int lr0 = ry0 - R0;
        const int j0  = c << 2;
        const int jm  = (c == 0) ? 0 : (j0 - 1);

        const float* row0 = &L[lr0 * WI];
        float4 v  = *reinterpret_cast<const float4*>(row0 + j0);
        float  vm = row0[jm];
        if (fy) {
            const int lr1 = min(ry0 + 1, 127) - R0;
            const float* row1 = &L[lr1 * WI];
            const float4 w  = *reinterpret_cast<const float4*>(row1 + j0);
            const float  wm = row1[jm];
            v.x = 0.5f * (v.x + w.x); v.y = 0.5f * (v.y + w.y);
            v.z = 0.5f * (v.z + w.z); v.w = 0.5f * (v.w + w.w);
            vm  = 0.5f * (vm + wm);
        }
        float4 r0, r1;
        r0.x = 0.5f * (vm + v.x);  r0.y = v.x;
        r0.z = 0.5f * (v.x + v.y); r0.w = v.y;
        r1.x = 0.5f * (v.y + v.z); r1.y = v.z;
        r1.z = 0.5f * (v.z + v.w); r1.w = v.w;

        float* o8 = O + (g << 3);
        *reinterpret_cast<float4*>(o8)     = r0;
        *reinterpret_cast<float4*>(o8 + 4) = r1;
    }
}

extern "C" void kernel_launch(void* const* d_in, const int* in_sizes, int n_in,
                              void* d_out, int out_size, void* d_ws, size_t ws_size,
                              hipStream_t stream) {
    const float* feats   = (const float*)d_in[0];
    const float* params  = (const float*)d_in[1];
    const float* locs    = (const float*)d_in[2];
    const float* soi     = (const float*)d_in[3];
    const int*   im_inds = (const int*)d_in[4];
    const int*   lvls    = (const int*)d_in[5];
    float*       out     = (float*)d_out;
    dynmask_kernel<<<512, 512, 0, stream>>>(feats, params, locs, soi, im_inds, lvls, out);
}

// Round 2
// 149.943 us; speedup vs baseline: 1.0207x; 1.0207x over previous
//
#include <hip/hip_runtime.h>

// DynamicMaskHead: fused CondInst mask-head MLP + aligned_bilinear x2 upsample.
// Grid: 512 blocks = 256 instances x 2 halves. Block: 512 threads.
// LDS: 65 logit rows (halo of 1) x 192 cols = 49,920 B.
// MLP math done on float2 ext-vectors -> v_pk_fma_f32 (2x fp32 rate on gfx950).

#define HI 128
#define WI 192
#define HW_ (HI * WI)        // 24576
#define NP 169
#define NOUT_W 384
#define NOUT_H 256

typedef float v2f __attribute__((ext_vector_type(2)));

__device__ __forceinline__ v2f splat(float x) { v2f r; r.x = x; r.y = x; return r; }
__device__ __forceinline__ v2f vfma(v2f a, v2f b, v2f c) {
    return __builtin_elementwise_fma(a, b, c);
}
__device__ __forceinline__ v2f vrelu(v2f a) {
    return __builtin_elementwise_max(a, splat(0.0f));
}

__global__ __launch_bounds__(512, 4) void dynmask_kernel(
    const float* __restrict__ feats,    // [2,8,128,192]
    const float* __restrict__ params,   // [256,169]
    const float* __restrict__ locs,     // [256,2]
    const float* __restrict__ soi,      // [5]
    const int*   __restrict__ im_inds,  // [256]
    const int*   __restrict__ lvls,     // [256]
    float*       __restrict__ out)      // [256,1,256,384]
{
    __shared__ __align__(16) float L[65 * WI];   // logit rows R0..R0+64

    const int b  = blockIdx.x;
    const int n  = b >> 1;       // instance
    const int hh = b & 1;        // half (0: out rows 0..127, 1: 128..255)
    const int t  = threadIdx.x;
    const int R0 = hh ? 63 : 0;  // first logit row held in LDS

    const int   im    = im_inds[n];
    const float s     = soi[lvls[n]];
    const float inv_s = 1.0f / s;
    const float ixv   = locs[2 * n + 0];
    const float iyv   = locs[2 * n + 1];
    const float* __restrict__ P = params + n * NP;   // block-uniform -> s_loads
    const float* __restrict__ F = feats + im * (8 * HW_);

    // rel_x(px) = (ixv - (px*8+4))/s = ax - px*step ; rel_y analogous
    const float step = 8.0f * inv_s;
    const float ax   = (ixv - 4.0f) * inv_s;
    const float ay   = (iyv - 4.0f) * inv_s;

    // ---------------- Phase 1: MLP -> logits in LDS ----------------
    // 65 rows * 192 cols = 12480 px = 3120 chunks of 4 px (contiguous).
    for (int idx = t; idx < 3120; idx += 512) {
        const int p   = R0 * WI + (idx << 2);    // global pixel (contiguous)
        const int py  = p / WI;
        const int px0 = p - py * WI;
        const float ry  = ay - (float)py * step;
        const float rx0 = ax - (float)px0 * step;
        v2f rxp[2];
        rxp[0].x = rx0;                rxp[0].y = rx0 - step;
        rxp[1].x = rx0 - 2.0f * step;  rxp[1].y = rx0 - 3.0f * step;

        v2f fv[8][2];
        #pragma unroll
        for (int k = 0; k < 8; ++k) {
            const float4 v = *reinterpret_cast<const float4*>(F + k * HW_ + p);
            fv[k][0].x = v.x; fv[k][0].y = v.y;
            fv[k][1].x = v.z; fv[k][1].y = v.w;
        }

        // layer 0: 10 -> 8, relu.  w0[o][i]=P[o*10+i], b0[o]=P[152+o]
        v2f h0[8][2];
        #pragma unroll
        for (int o = 0; o < 8; ++o) {
            const float base = fmaf(P[o * 10 + 1], ry, P[152 + o]);
            const v2f   bv   = splat(base);
            const v2f   wx   = splat(P[o * 10 + 0]);
            h0[o][0] = vfma(wx, rxp[0], bv);
            h0[o][1] = vfma(wx, rxp[1], bv);
            #pragma unroll
            for (int k = 0; k < 8; ++k) {
                const v2f w = splat(P[o * 10 + 2 + k]);
                h0[o][0] = vfma(w, fv[k][0], h0[o][0]);
                h0[o][1] = vfma(w, fv[k][1], h0[o][1]);
            }
            h0[o][0] = vrelu(h0[o][0]);
            h0[o][1] = vrelu(h0[o][1]);
        }

        // layer 1: 8 -> 8, relu.  w1[o][i]=P[80+o*8+i], b1[o]=P[160+o]
        v2f h1[8][2];
        #pragma unroll
        for (int o = 0; o < 8; ++o) {
            const v2f bb = splat(P[160 + o]);
            h1[o][0] = bb;
            h1[o][1] = bb;
            #pragma unroll
            for (int i = 0; i < 8; ++i) {
                const v2f w = splat(P[80 + o * 8 + i]);
                h1[o][0] = vfma(w, h0[i][0], h1[o][0]);
                h1[o][1] = vfma(w, h0[i][1], h1[o][1]);
            }
            h1[o][0] = vrelu(h1[o][0]);
            h1[o][1] = vrelu(h1[o][1]);
        }

        // layer 2: 8 -> 1.  w2[i]=P[144+i], b2=P[168]
        v2f lg[2];
        lg[0] = splat(P[168]);
        lg[1] = lg[0];
        #pragma unroll
        for (int i = 0; i < 8; ++i) {
            const v2f w = splat(P[144 + i]);
            lg[0] = vfma(w, h1[i][0], lg[0]);
            lg[1] = vfma(w, h1[i][1], lg[1]);
        }

        float4 st;
        st.x = lg[0].x; st.y = lg[0].y; st.z = lg[1].x; st.w = lg[1].y;
        *reinterpret_cast<float4*>(&L[idx << 2]) = st;
    }

    __syncthreads();

    // ---------------- Phase 2: aligned_bilinear x2 ----------------
    // out[y][x] = interp[max(y-1,0)][max(x-1,0)]
    //   rows: ry0=(iy)>>1, fy=iy&1 -> row ry0 or avg(ry0, min(ry0+1,127))
    //   cols: out[2m]=0.5*(v[m-1]+v[m]) (clamp m-1>=0), out[2m+1]=v[m]
    // Each thread: 8 output px from a float4 of v (+1 left neighbor).
    const int Y0 = hh << 7;
    float* __restrict__ O = out + n * (NOUT_H * NOUT_W) + Y0 * NOUT_W;
    for (int g = t; g < 6144; g += 512) {     // 128 rows * 48 groups
        const int yq = g / 48;
        const int c  = g - yq * 48;
        const int y  = Y0 + yq;
        const int iy2 = (y == 0) ? 0 : (y - 1);
        const int ry0 = iy2 >> 1;
        const int fy  = iy2 & 1;
        const int lr0 = ry0 - R0;
        const int j0  = c << 2;
        const int jm  = (c == 0) ? 0 : (j0 - 1);

        const float* row0 = &L[lr0 * WI];
        float4 v  = *reinterpret_cast<const float4*>(row0 + j0);
        float  vm = row0[jm];
        if (fy) {
            const int lr1 = min(ry0 + 1, 127) - R0;
            const float* row1 = &L[lr1 * WI];
            const float4 w  = *reinterpret_cast<const float4*>(row1 + j0);
            const float  wm = row1[jm];
            v.x = 0.5f * (v.x + w.x); v.y = 0.5f * (v.y + w.y);
            v.z = 0.5f * (v.z + w.z); v.w = 0.5f * (v.w + w.w);
            vm  = 0.5f * (vm + wm);
        }
        float4 r0, r1;
        r0.x = 0.5f * (vm + v.x);  r0.y = v.x;
        r0.z = 0.5f * (v.x + v.y); r0.w = v.y;
        r1.x = 0.5f * (v.y + v.z); r1.y = v.z;
        r1.z = 0.5f * (v.z + v.w); r1.w = v.w;

        float* o8 = O + (g << 3);
        *reinterpret_cast<float4*>(o8)     = r0;
        *reinterpret_cast<float4*>(o8 + 4) = r1;
    }
}

extern "C" void kernel_launch(void* const* d_in, const int* in_sizes, int n_in,
                              void* d_out, int out_size, void* d_ws, size_t ws_size,
                              hipStream_t stream) {
    const float* feats   = (const float*)d_in[0];
    const float* params  = (const float*)d_in[1];
    const float* locs    = (const float*)d_in[2];
    const float* soi     = (const float*)d_in[3];
    const int*   im_inds = (const int*)d_in[4];
    const int*   lvls    = (const int*)d_in[5];
    float*       out     = (float*)d_out;
    dynmask_kernel<<<512, 512, 0, stream>>>(feats, params, locs, soi, im_inds, lvls, out);
}